// Round 3
// baseline (630.866 us; speedup 1.0000x reference)
//
#include <hip/hip_runtime.h>

#define DMODEL 512
#define NHEADS 8
#define DK 64
#define BSZ 4
#define NE 1024
#define NNODE 4096

typedef __attribute__((ext_vector_type(8))) __bf16 bf16x8;
typedef __attribute__((ext_vector_type(4))) float f32x4;
typedef __attribute__((ext_vector_type(8))) unsigned short u16x8;
typedef __attribute__((ext_vector_type(4))) unsigned short u16x4;

static __device__ __forceinline__ unsigned short f2bf(float f) {
    union { float f; unsigned int u; } v; v.f = f;
    unsigned int u = v.u;
    return (unsigned short)((u + 0x7FFFu + ((u >> 16) & 1u)) >> 16);
}

// v_cvt_pk_bf16_f32: D[15:0]=bf16(lo), D[31:16]=bf16(hi), RNE
static __device__ __forceinline__ unsigned cvtpk(float lo, float hi) {
    unsigned r;
    asm("v_cvt_pk_bf16_f32 %0, %1, %2" : "=v"(r) : "v"(lo), "v"(hi));
    return r;
}

static __device__ __forceinline__ bf16x8 ldb8(const unsigned short* p) {
    return *reinterpret_cast<const bf16x8*>(p);
}

// ---------------- 4-weight f32 -> bf16 conversion, one launch ----------------
// dst: wq|wk|wv|wo contiguous, each 512*512 bf16. 131072 groups of 8 elems.
__global__ __launch_bounds__(256) void convw4(const float4* __restrict__ a,
                                              const float4* __restrict__ b,
                                              const float4* __restrict__ c,
                                              const float4* __restrict__ d,
                                              u16x8* __restrict__ dst) {
    int i = blockIdx.x * 256 + threadIdx.x;  // 0..131071
    int sel = i >> 15;
    const float4* s = sel == 0 ? a : sel == 1 ? b : sel == 2 ? c : d;
    int j = i & 32767;
    float4 x = s[2 * j];
    float4 y = s[2 * j + 1];
    unsigned u0 = cvtpk(x.x, x.y), u1 = cvtpk(x.z, x.w);
    unsigned u2 = cvtpk(y.x, y.y), u3 = cvtpk(y.z, y.w);
    u16x8 o;
    o[0] = (unsigned short)u0; o[1] = (unsigned short)(u0 >> 16);
    o[2] = (unsigned short)u1; o[3] = (unsigned short)(u1 >> 16);
    o[4] = (unsigned short)u2; o[5] = (unsigned short)(u2 >> 16);
    o[6] = (unsigned short)u3; o[7] = (unsigned short)(u3 >> 16);
    dst[i] = o;
}

// ---------------- mask bit-pack: inc int32 (BS*E*N) -> u64 bitgroups ----------------
// group g covers flat inc[g*64 .. g*64+63]; bit j = (inc!=0). 262144 groups.
__global__ __launch_bounds__(256) void maskpack(const int* __restrict__ inc,
                                                unsigned long long* __restrict__ mb) {
    int g = blockIdx.x * 4 + (threadIdx.x >> 6);
    int lane = threadIdx.x & 63;
    int v = inc[(size_t)g * 64 + lane];
    unsigned long long m = __ballot(v != 0);
    if (lane == 0) mb[g] = m;
}

// ---------------- NT GEMM: C[m][n] = (sum_k A[m][k]*W[n][k] + bias[n]) * oscale ----
// A: M x 512 (f32 if AF32 else bf16), W: 512x512 bf16 row-major. Block 4 waves,
// tile 64M x (NT*16)N. MODE 0: bf16 out; MODE 1: transposed V-layout bf16 out;
// MODE 2: f32 out.
template <int MODE, int NT, bool AF32>
__global__ __launch_bounds__(256) void gemm_nt(const void* __restrict__ Av,
                                               const unsigned short* __restrict__ W,
                                               const float* __restrict__ bias,
                                               void* __restrict__ Cout, float oscale) {
    const int K = DMODEL;
    int w = threadIdx.x >> 6, l = threadIdx.x & 63;
    int lr = l & 15, lh = l >> 4;
    int m0 = blockIdx.x * 64 + w * 16;
    int n0 = blockIdx.y * (NT * 16);

    f32x4 acc[NT] = {};

#pragma unroll 4
    for (int k0 = 0; k0 < K; k0 += 32) {
        bf16x8 a;
        if constexpr (AF32) {
            const float* Af = (const float*)Av + (size_t)(m0 + lr) * K + k0 + lh * 8;
            float4 x = *reinterpret_cast<const float4*>(Af);
            float4 y = *reinterpret_cast<const float4*>(Af + 4);
            unsigned u0 = cvtpk(x.x, x.y), u1 = cvtpk(x.z, x.w);
            unsigned u2 = cvtpk(y.x, y.y), u3 = cvtpk(y.z, y.w);
            u16x8 t8;
            t8[0] = (unsigned short)u0; t8[1] = (unsigned short)(u0 >> 16);
            t8[2] = (unsigned short)u1; t8[3] = (unsigned short)(u1 >> 16);
            t8[4] = (unsigned short)u2; t8[5] = (unsigned short)(u2 >> 16);
            t8[6] = (unsigned short)u3; t8[7] = (unsigned short)(u3 >> 16);
            a = __builtin_bit_cast(bf16x8, t8);
        } else {
            a = ldb8((const unsigned short*)Av + (size_t)(m0 + lr) * K + k0 + lh * 8);
        }
#pragma unroll
        for (int t = 0; t < NT; ++t) {
            bf16x8 b = ldb8(W + (size_t)(n0 + t * 16 + lr) * K + k0 + lh * 8);
            acc[t] = __builtin_amdgcn_mfma_f32_16x16x32_bf16(a, b, acc[t], 0, 0, 0);
        }
    }

    if constexpr (MODE == 0) {
        unsigned short* C = (unsigned short*)Cout;
#pragma unroll
        for (int t = 0; t < NT; ++t) {
            float bv = bias[n0 + t * 16 + lr];
#pragma unroll
            for (int r = 0; r < 4; ++r) {
                C[(size_t)(m0 + lh * 4 + r) * DMODEL + n0 + t * 16 + lr] =
                    f2bf((acc[t][r] + bv) * oscale);
            }
        }
    } else if constexpr (MODE == 1) {
        // rows of A are (b*4096 + node); cols are h*64 + d
        unsigned short* Vt = (unsigned short*)Cout;
        int bb = m0 >> 12;
        int node0 = (m0 & (NNODE - 1)) + lh * 4;
#pragma unroll
        for (int t = 0; t < NT; ++t) {
            int n = n0 + t * 16;
            int hh = n >> 6;
            int dd = (n & 63) + lr;
            float bv = bias[n + lr];
            u16x4 pk;
#pragma unroll
            for (int r = 0; r < 4; ++r) pk[r] = f2bf((acc[t][r] + bv) * oscale);
            *reinterpret_cast<u16x4*>(Vt + (size_t)((bb * NHEADS + hh) * DK + dd) * NNODE +
                                      node0) = pk;
        }
    } else {
        float* C = (float*)Cout;
#pragma unroll
        for (int t = 0; t < NT; ++t) {
            float bv = bias[n0 + t * 16 + lr];
#pragma unroll
            for (int r = 0; r < 4; ++r) {
                C[(size_t)(m0 + lh * 4 + r) * DMODEL + n0 + t * 16 + lr] =
                    (acc[t][r] + bv) * oscale;
            }
        }
    }
}

// ---------------- fused masked attention, fixed-shift softmax, node-split ----------
// Qb pre-scaled by 1/8. Block = (b, 16-edge tile, head h); 4 waves split 4096 nodes
// 4-way (1024 each); in-LDS combine at the end. p = maskbit * exp(s); l summed
// per-lane, reduced once in epilogue (no online max: s ~ N(0,1), no overflow risk).
__global__ __launch_bounds__(256, 6) void attn_kernel(
    const unsigned short* __restrict__ Qb, const unsigned short* __restrict__ Kb,
    const unsigned short* __restrict__ Vt, const unsigned long long* __restrict__ mbits,
    unsigned short* __restrict__ Ob) {
    int w = threadIdx.x >> 6, l = threadIdx.x & 63;
    int lr = l & 15, lh = l >> 4;
    int bx = blockIdx.x;
    int b = bx >> 6, e0 = (bx & 63) * 16;
    int h = blockIdx.y;

    // union: main loop uses per-wave P tiles (wave w: bytes [w*2432, (w+1)*2432));
    // epilogue (after syncthreads) reuses whole region as Of[4][16][65] f32.
    __shared__ float smem[4][16][65];
    __shared__ float sLf[4][16];
    unsigned short* Pw = (unsigned short*)(&smem[0][0][0]) + w * (16 * 76);

    const unsigned short* Qrow = Qb + (size_t)(b * NE + e0 + lr) * DMODEL + h * DK;
    bf16x8 q0 = ldb8(Qrow + lh * 8);
    bf16x8 q1 = ldb8(Qrow + 32 + lh * 8);

    const unsigned short* Kbase = Kb + (size_t)(b * NNODE + w * 1024) * DMODEL + h * DK;
    const unsigned short* Vbase =
        Vt + (size_t)((b * NHEADS + h) * DK) * NNODE + w * 1024;
    const unsigned long long* mrow = mbits + (size_t)(b * NE + e0) * 64 + w * 16;

    f32x4 oacc[4] = {};
    float lsum[4] = {0.f, 0.f, 0.f, 0.f};

    for (int cb = 0; cb < 16; ++cb) {
        // ---- S = Q K^T over 64 nodes ----
        f32x4 s[4] = {};
#pragma unroll
        for (int t = 0; t < 4; ++t) {
            const unsigned short* Krow = Kbase + (size_t)(cb * 64 + t * 16 + lr) * DMODEL;
            bf16x8 k0 = ldb8(Krow + lh * 8);
            bf16x8 k1 = ldb8(Krow + 32 + lh * 8);
            s[t] = __builtin_amdgcn_mfma_f32_16x16x32_bf16(q0, k0, s[t], 0, 0, 0);
            s[t] = __builtin_amdgcn_mfma_f32_16x16x32_bf16(q1, k1, s[t], 0, 0, 0);
        }
        // ---- mask words (broadcast across 16 lanes) ----
        unsigned mlo[4], mhi[4];
#pragma unroll
        for (int r = 0; r < 4; ++r) {
            unsigned long long mw = mrow[(lh * 4 + r) * 64 + cb];
            mlo[r] = (unsigned)mw;
            mhi[r] = (unsigned)(mw >> 32);
        }
        // ---- p = bit * exp(s); accumulate l; pack to LDS ----
#pragma unroll
        for (int t = 0; t < 4; ++t) {
#pragma unroll
            for (int r = 0; r < 4; ++r) {
                float p = __expf(s[t][r]);
                unsigned bits = (t < 2 ? mlo[r] : mhi[r]) >> ((t & 1) * 16 + lr);
                p = (bits & 1u) ? p : 0.0f;
                s[t][r] = p;
                lsum[r] += p;
            }
            unsigned p01 = cvtpk(s[t][0], s[t][1]);
            unsigned p23 = cvtpk(s[t][2], s[t][3]);
            Pw[(lh * 4 + 0) * 76 + t * 16 + lr] = (unsigned short)p01;
            Pw[(lh * 4 + 1) * 76 + t * 16 + lr] = (unsigned short)(p01 >> 16);
            Pw[(lh * 4 + 2) * 76 + t * 16 + lr] = (unsigned short)p23;
            Pw[(lh * 4 + 3) * 76 + t * 16 + lr] = (unsigned short)(p23 >> 16);
        }
        // ---- O += P @ V (same-wave LDS RAW; compiler inserts lgkmcnt) ----
#pragma unroll
        for (int kk = 0; kk < 2; ++kk) {
            bf16x8 pa = ldb8(Pw + lr * 76 + kk * 32 + lh * 8);
#pragma unroll
            for (int dt = 0; dt < 4; ++dt) {
                bf16x8 vb = ldb8(Vbase + (size_t)(dt * 16 + lr) * NNODE + cb * 64 +
                                 kk * 32 + lh * 8);
                oacc[dt] = __builtin_amdgcn_mfma_f32_16x16x32_bf16(pa, vb, oacc[dt], 0, 0, 0);
            }
        }
    }

    // ---- epilogue: reduce l across 16 lanes, combine 4 node-segments in LDS ----
#pragma unroll
    for (int r = 0; r < 4; ++r) {
        float v = lsum[r];
        v += __shfl_xor(v, 1);
        v += __shfl_xor(v, 2);
        v += __shfl_xor(v, 4);
        v += __shfl_xor(v, 8);
        lsum[r] = v;
    }
    __syncthreads();  // all waves done with their P tiles before Of overwrites them
#pragma unroll
    for (int t = 0; t < 4; ++t)
#pragma unroll
        for (int r = 0; r < 4; ++r) smem[w][lh * 4 + r][t * 16 + lr] = oacc[t][r];
    if (lr == 0) {
#pragma unroll
        for (int r = 0; r < 4; ++r) sLf[w][lh * 4 + r] = lsum[r];
    }
    __syncthreads();
    // wave w writes column block w
#pragma unroll
    for (int r = 0; r < 4; ++r) {
        int row = lh * 4 + r;
        float o = smem[0][row][w * 16 + lr] + smem[1][row][w * 16 + lr] +
                  smem[2][row][w * 16 + lr] + smem[3][row][w * 16 + lr];
        float L = sLf[0][row] + sLf[1][row] + sLf[2][row] + sLf[3][row];
        Ob[(size_t)(b * NE + e0 + row) * DMODEL + h * DK + w * 16 + lr] = f2bf(o / L);
    }
}

// ---------------- launch ----------------
extern "C" void kernel_launch(void* const* d_in, const int* in_sizes, int n_in,
                              void* d_out, int out_size, void* d_ws, size_t ws_size,
                              hipStream_t stream) {
    const float* queries = (const float*)d_in[0];
    const float* keys = (const float*)d_in[1];
    const int* inc = (const int*)d_in[2];
    const float* Wq = (const float*)d_in[3];
    const float* bq = (const float*)d_in[4];
    const float* Wk = (const float*)d_in[5];
    const float* bk = (const float*)d_in[6];
    const float* Wv = (const float*)d_in[7];
    const float* bv = (const float*)d_in[8];
    const float* Wo = (const float*)d_in[9];
    const float* bo = (const float*)d_in[10];

    unsigned long long* mbits = (unsigned long long*)d_ws;          // 262144 u64 = 2 MB
    unsigned short* wqb = (unsigned short*)(mbits + BSZ * NE * 64); // 4 x 512*512 bf16
    unsigned short* wkb = wqb + DMODEL * DMODEL;
    unsigned short* wvb = wkb + DMODEL * DMODEL;
    unsigned short* wob = wvb + DMODEL * DMODEL;
    unsigned short* Qb = wob + DMODEL * DMODEL;                     // BS*E*512
    unsigned short* Kb = Qb + (size_t)BSZ * NE * DMODEL;            // BS*N*512
    unsigned short* Vt = Kb + (size_t)BSZ * NNODE * DMODEL;         // BS*8*64 x 4096
    unsigned short* Ob = Vt + (size_t)BSZ * NNODE * DMODEL;         // BS*E*512

    convw4<<<512, 256, 0, stream>>>((const float4*)Wq, (const float4*)Wk,
                                    (const float4*)Wv, (const float4*)Wo, (u16x8*)wqb);
    maskpack<<<BSZ * NE * 64 / 4, 256, 0, stream>>>(inc, mbits);

    // Q projection pre-scaled by 1/sqrt(d_k) = 1/8
    gemm_nt<0, 4, true><<<dim3(BSZ * NE / 64, 8), 256, 0, stream>>>(queries, wqb, bq, Qb,
                                                                    0.125f);
    gemm_nt<0, 8, true><<<dim3(BSZ * NNODE / 64, 4), 256, 0, stream>>>(keys, wkb, bk, Kb,
                                                                       1.0f);
    gemm_nt<1, 8, true><<<dim3(BSZ * NNODE / 64, 4), 256, 0, stream>>>(keys, wvb, bv, Vt,
                                                                       1.0f);

    attn_kernel<<<dim3(BSZ * 64, NHEADS), 256, 0, stream>>>(Qb, Kb, Vt, mbits, Ob);

    gemm_nt<2, 4, false><<<dim3(BSZ * NE / 64, 8), 256, 0, stream>>>(Ob, wob, bo, d_out,
                                                                     1.0f);
}

// Round 4
// 601.858 us; speedup vs baseline: 1.0482x; 1.0482x over previous
//
#include <hip/hip_runtime.h>

#define DMODEL 512
#define NHEADS 8
#define DK 64
#define BSZ 4
#define NE 1024
#define NNODE 4096

typedef __attribute__((ext_vector_type(8))) __bf16 bf16x8;
typedef __attribute__((ext_vector_type(4))) float f32x4;
typedef __attribute__((ext_vector_type(8))) unsigned short u16x8;
typedef __attribute__((ext_vector_type(4))) unsigned short u16x4;

static __device__ __forceinline__ unsigned short f2bf(float f) {
    union { float f; unsigned int u; } v; v.f = f;
    unsigned int u = v.u;
    return (unsigned short)((u + 0x7FFFu + ((u >> 16) & 1u)) >> 16);
}

// v_cvt_pk_bf16_f32: D[15:0]=bf16(lo), D[31:16]=bf16(hi), RNE
static __device__ __forceinline__ unsigned cvtpk(float lo, float hi) {
    unsigned r;
    asm("v_cvt_pk_bf16_f32 %0, %1, %2" : "=v"(r) : "v"(lo), "v"(hi));
    return r;
}

static __device__ __forceinline__ bf16x8 ldb8(const unsigned short* p) {
    return *reinterpret_cast<const bf16x8*>(p);
}

// ---------------- 4-weight f32 -> bf16 conversion, one launch ----------------
__global__ __launch_bounds__(256) void convw4(const float4* __restrict__ a,
                                              const float4* __restrict__ b,
                                              const float4* __restrict__ c,
                                              const float4* __restrict__ d,
                                              u16x8* __restrict__ dst) {
    int i = blockIdx.x * 256 + threadIdx.x;  // 0..131071
    int sel = i >> 15;
    const float4* s = sel == 0 ? a : sel == 1 ? b : sel == 2 ? c : d;
    int j = i & 32767;
    float4 x = s[2 * j];
    float4 y = s[2 * j + 1];
    unsigned u0 = cvtpk(x.x, x.y), u1 = cvtpk(x.z, x.w);
    unsigned u2 = cvtpk(y.x, y.y), u3 = cvtpk(y.z, y.w);
    u16x8 o;
    o[0] = (unsigned short)u0; o[1] = (unsigned short)(u0 >> 16);
    o[2] = (unsigned short)u1; o[3] = (unsigned short)(u1 >> 16);
    o[4] = (unsigned short)u2; o[5] = (unsigned short)(u2 >> 16);
    o[6] = (unsigned short)u3; o[7] = (unsigned short)(u3 >> 16);
    dst[i] = o;
}

// ---------------- mask bit-pack: inc int32 (BS*E*N) -> u64 bitgroups ----------------
__global__ __launch_bounds__(256) void maskpack(const int* __restrict__ inc,
                                                unsigned long long* __restrict__ mb) {
    int g = blockIdx.x * 4 + (threadIdx.x >> 6);
    int lane = threadIdx.x & 63;
    int v = inc[(size_t)g * 64 + lane];
    unsigned long long m = __ballot(v != 0);
    if (lane == 0) mb[g] = m;
}

// ---------------- NT GEMM: C[m][n] = (sum_k A[m][k]*W[n][k] + bias[n]) * oscale ----
template <int MODE, int NT, bool AF32>
__global__ __launch_bounds__(256) void gemm_nt(const void* __restrict__ Av,
                                               const unsigned short* __restrict__ W,
                                               const float* __restrict__ bias,
                                               void* __restrict__ Cout, float oscale) {
    const int K = DMODEL;
    int w = threadIdx.x >> 6, l = threadIdx.x & 63;
    int lr = l & 15, lh = l >> 4;
    int m0 = blockIdx.x * 64 + w * 16;
    int n0 = blockIdx.y * (NT * 16);

    f32x4 acc[NT] = {};

#pragma unroll 4
    for (int k0 = 0; k0 < K; k0 += 32) {
        bf16x8 a;
        if constexpr (AF32) {
            const float* Af = (const float*)Av + (size_t)(m0 + lr) * K + k0 + lh * 8;
            float4 x = *reinterpret_cast<const float4*>(Af);
            float4 y = *reinterpret_cast<const float4*>(Af + 4);
            unsigned u0 = cvtpk(x.x, x.y), u1 = cvtpk(x.z, x.w);
            unsigned u2 = cvtpk(y.x, y.y), u3 = cvtpk(y.z, y.w);
            u16x8 t8;
            t8[0] = (unsigned short)u0; t8[1] = (unsigned short)(u0 >> 16);
            t8[2] = (unsigned short)u1; t8[3] = (unsigned short)(u1 >> 16);
            t8[4] = (unsigned short)u2; t8[5] = (unsigned short)(u2 >> 16);
            t8[6] = (unsigned short)u3; t8[7] = (unsigned short)(u3 >> 16);
            a = __builtin_bit_cast(bf16x8, t8);
        } else {
            a = ldb8((const unsigned short*)Av + (size_t)(m0 + lr) * K + k0 + lh * 8);
        }
#pragma unroll
        for (int t = 0; t < NT; ++t) {
            bf16x8 b = ldb8(W + (size_t)(n0 + t * 16 + lr) * K + k0 + lh * 8);
            acc[t] = __builtin_amdgcn_mfma_f32_16x16x32_bf16(a, b, acc[t], 0, 0, 0);
        }
    }

    if constexpr (MODE == 0) {
        unsigned short* C = (unsigned short*)Cout;
#pragma unroll
        for (int t = 0; t < NT; ++t) {
            float bv = bias[n0 + t * 16 + lr];
#pragma unroll
            for (int r = 0; r < 4; ++r) {
                C[(size_t)(m0 + lh * 4 + r) * DMODEL + n0 + t * 16 + lr] =
                    f2bf((acc[t][r] + bv) * oscale);
            }
        }
    } else if constexpr (MODE == 1) {
        // rows of A are (b*4096 + node); cols are h*64 + d
        unsigned short* Vt = (unsigned short*)Cout;
        int bb = m0 >> 12;
        int node0 = (m0 & (NNODE - 1)) + lh * 4;
#pragma unroll
        for (int t = 0; t < NT; ++t) {
            int n = n0 + t * 16;
            int hh = n >> 6;
            int dd = (n & 63) + lr;
            float bv = bias[n + lr];
            u16x4 pk;
#pragma unroll
            for (int r = 0; r < 4; ++r) pk[r] = f2bf((acc[t][r] + bv) * oscale);
            *reinterpret_cast<u16x4*>(Vt + (size_t)((bb * NHEADS + hh) * DK + dd) * NNODE +
                                      node0) = pk;
        }
    } else {
        float* C = (float*)Cout;
#pragma unroll
        for (int t = 0; t < NT; ++t) {
            float bv = bias[n0 + t * 16 + lr];
#pragma unroll
            for (int r = 0; r < 4; ++r) {
                C[(size_t)(m0 + lh * 4 + r) * DMODEL + n0 + t * 16 + lr] =
                    (acc[t][r] + bv) * oscale;
            }
        }
    }
}

// ---------------- fused masked attention, prefetched ping-pong pipeline ----------
// Grid: 2048 blocks, 1-D, XCD-swizzled so all 64 e-tiles of one (b,h) pair land on
// one XCD (pair working set K+V = 1 MB -> L2-resident). 4 waves split nodes 4-way.
// Per chunk of 64 nodes: K/V/mask prefetched one chunk ahead in registers.
__global__ __launch_bounds__(256) void attn_kernel(
    const unsigned short* __restrict__ Qb, const unsigned short* __restrict__ Kb,
    const unsigned short* __restrict__ Vt, const unsigned long long* __restrict__ mbits,
    unsigned short* __restrict__ Ob) {
    int w = threadIdx.x >> 6, l = threadIdx.x & 63;
    int lr = l & 15, lh = l >> 4;
    // swizzle: id = xcd | (et<<3) | (pairslot<<9); pair = xcd*4 + pairslot
    int id = blockIdx.x;
    int xcd = id & 7;
    int et = (id >> 3) & 63;
    int ps = id >> 9;
    int pair = xcd * 4 + ps;
    int b = pair >> 3, h = pair & 7;
    int e0 = et * 16;

    __shared__ float smem[4][16][65];
    __shared__ float sLf[4][16];
    unsigned short* Pw = (unsigned short*)(&smem[0][0][0]) + w * (16 * 76);

    const unsigned short* Qrow = Qb + (size_t)(b * NE + e0 + lr) * DMODEL + h * DK;
    bf16x8 q0 = ldb8(Qrow + lh * 8);
    bf16x8 q1 = ldb8(Qrow + 32 + lh * 8);

    const unsigned short* Kbase = Kb + (size_t)(b * NNODE + w * 1024) * DMODEL + h * DK;
    const unsigned short* Vbase =
        Vt + (size_t)((b * NHEADS + h) * DK) * NNODE + w * 1024;
    const unsigned long long* mrow = mbits + (size_t)(b * NE + e0) * 64 + w * 16;

    f32x4 oacc[4] = {};
    float lsum[4] = {0.f, 0.f, 0.f, 0.f};

    auto loadchunk = [&](int cb, bf16x8* kk, bf16x8* vv, unsigned long long* mm) {
#pragma unroll
        for (int t = 0; t < 4; ++t) {
            const unsigned short* Krow = Kbase + (size_t)(cb * 64 + t * 16 + lr) * DMODEL;
            kk[2 * t] = ldb8(Krow + lh * 8);
            kk[2 * t + 1] = ldb8(Krow + 32 + lh * 8);
        }
#pragma unroll
        for (int k2 = 0; k2 < 2; ++k2)
#pragma unroll
            for (int dt = 0; dt < 4; ++dt)
                vv[k2 * 4 + dt] = ldb8(Vbase + (size_t)(dt * 16 + lr) * NNODE + cb * 64 +
                                       k2 * 32 + lh * 8);
#pragma unroll
        for (int r = 0; r < 4; ++r) mm[r] = mrow[(lh * 4 + r) * 64 + cb];
    };

    auto computechunk = [&](const bf16x8* kk, const bf16x8* vv,
                            const unsigned long long* mm) {
        f32x4 s[4] = {};
#pragma unroll
        for (int t = 0; t < 4; ++t) {
            s[t] = __builtin_amdgcn_mfma_f32_16x16x32_bf16(q0, kk[2 * t], s[t], 0, 0, 0);
            s[t] = __builtin_amdgcn_mfma_f32_16x16x32_bf16(q1, kk[2 * t + 1], s[t], 0, 0, 0);
        }
#pragma unroll
        for (int t = 0; t < 4; ++t) {
#pragma unroll
            for (int r = 0; r < 4; ++r) {
                float p = __expf(s[t][r]);
                unsigned half = (t < 2) ? (unsigned)mm[r] : (unsigned)(mm[r] >> 32);
                unsigned bits = half >> ((t & 1) * 16 + lr);
                p = (bits & 1u) ? p : 0.0f;
                s[t][r] = p;
                lsum[r] += p;
            }
            unsigned p01 = cvtpk(s[t][0], s[t][1]);
            unsigned p23 = cvtpk(s[t][2], s[t][3]);
            Pw[(lh * 4 + 0) * 76 + t * 16 + lr] = (unsigned short)p01;
            Pw[(lh * 4 + 1) * 76 + t * 16 + lr] = (unsigned short)(p01 >> 16);
            Pw[(lh * 4 + 2) * 76 + t * 16 + lr] = (unsigned short)p23;
            Pw[(lh * 4 + 3) * 76 + t * 16 + lr] = (unsigned short)(p23 >> 16);
        }
#pragma unroll
        for (int k2 = 0; k2 < 2; ++k2) {
            bf16x8 pa = ldb8(Pw + lr * 76 + k2 * 32 + lh * 8);
#pragma unroll
            for (int dt = 0; dt < 4; ++dt) {
                oacc[dt] = __builtin_amdgcn_mfma_f32_16x16x32_bf16(pa, vv[k2 * 4 + dt],
                                                                   oacc[dt], 0, 0, 0);
            }
        }
    };

    bf16x8 kA[8], vA[8], kB[8], vB[8];
    unsigned long long mA[4], mB[4];

    loadchunk(0, kA, vA, mA);
#pragma unroll
    for (int i = 0; i < 8; ++i) {
        loadchunk(2 * i + 1, kB, vB, mB);
        computechunk(kA, vA, mA);
        if (i < 7) loadchunk(2 * i + 2, kA, vA, mA);
        computechunk(kB, vB, mB);
    }

    // ---- epilogue: reduce l across 16 lanes, combine 4 node-segments in LDS ----
#pragma unroll
    for (int r = 0; r < 4; ++r) {
        float v = lsum[r];
        v += __shfl_xor(v, 1);
        v += __shfl_xor(v, 2);
        v += __shfl_xor(v, 4);
        v += __shfl_xor(v, 8);
        lsum[r] = v;
    }
    __syncthreads();
#pragma unroll
    for (int t = 0; t < 4; ++t)
#pragma unroll
        for (int r = 0; r < 4; ++r) smem[w][lh * 4 + r][t * 16 + lr] = oacc[t][r];
    if (lr == 0) {
#pragma unroll
        for (int r = 0; r < 4; ++r) sLf[w][lh * 4 + r] = lsum[r];
    }
    __syncthreads();
#pragma unroll
    for (int r = 0; r < 4; ++r) {
        int row = lh * 4 + r;
        float o = smem[0][row][w * 16 + lr] + smem[1][row][w * 16 + lr] +
                  smem[2][row][w * 16 + lr] + smem[3][row][w * 16 + lr];
        float L = sLf[0][row] + sLf[1][row] + sLf[2][row] + sLf[3][row];
        Ob[(size_t)(b * NE + e0 + row) * DMODEL + h * DK + w * 16 + lr] = f2bf(o / L);
    }
}

// ---------------- launch ----------------
extern "C" void kernel_launch(void* const* d_in, const int* in_sizes, int n_in,
                              void* d_out, int out_size, void* d_ws, size_t ws_size,
                              hipStream_t stream) {
    const float* queries = (const float*)d_in[0];
    const float* keys = (const float*)d_in[1];
    const int* inc = (const int*)d_in[2];
    const float* Wq = (const float*)d_in[3];
    const float* bq = (const float*)d_in[4];
    const float* Wk = (const float*)d_in[5];
    const float* bk = (const float*)d_in[6];
    const float* Wv = (const float*)d_in[7];
    const float* bv = (const float*)d_in[8];
    const float* Wo = (const float*)d_in[9];
    const float* bo = (const float*)d_in[10];

    unsigned long long* mbits = (unsigned long long*)d_ws;          // 262144 u64 = 2 MB
    unsigned short* wqb = (unsigned short*)(mbits + BSZ * NE * 64); // 4 x 512*512 bf16
    unsigned short* wkb = wqb + DMODEL * DMODEL;
    unsigned short* wvb = wkb + DMODEL * DMODEL;
    unsigned short* wob = wvb + DMODEL * DMODEL;
    unsigned short* Qb = wob + DMODEL * DMODEL;                     // BS*E*512
    unsigned short* Kb = Qb + (size_t)BSZ * NE * DMODEL;            // BS*N*512
    unsigned short* Vt = Kb + (size_t)BSZ * NNODE * DMODEL;         // BS*8*64 x 4096
    unsigned short* Ob = Vt + (size_t)BSZ * NNODE * DMODEL;         // BS*E*512

    convw4<<<512, 256, 0, stream>>>((const float4*)Wq, (const float4*)Wk,
                                    (const float4*)Wv, (const float4*)Wo, (u16x8*)wqb);
    maskpack<<<BSZ * NE * 64 / 4, 256, 0, stream>>>(inc, mbits);

    // Q projection pre-scaled by 1/sqrt(d_k) = 1/8
    gemm_nt<0, 4, true><<<dim3(BSZ * NE / 64, 8), 256, 0, stream>>>(queries, wqb, bq, Qb,
                                                                    0.125f);
    gemm_nt<0, 16, true><<<dim3(BSZ * NNODE / 64, 2), 256, 0, stream>>>(keys, wkb, bk, Kb,
                                                                        1.0f);
    gemm_nt<1, 16, true><<<dim3(BSZ * NNODE / 64, 2), 256, 0, stream>>>(keys, wvb, bv, Vt,
                                                                        1.0f);

    attn_kernel<<<dim3(BSZ * 64 * NHEADS), 256, 0, stream>>>(Qb, Kb, Vt, mbits, Ob);

    gemm_nt<2, 4, false><<<dim3(BSZ * NE / 64, 8), 256, 0, stream>>>(Ob, wob, bo, d_out,
                                                                     1.0f);
}

// Round 5
// 468.848 us; speedup vs baseline: 1.3456x; 1.2837x over previous
//
#include <hip/hip_runtime.h>

#define DMODEL 512
#define NHEADS 8
#define DK 64
#define BSZ 4
#define NE 1024
#define NNODE 4096

typedef __attribute__((ext_vector_type(8))) __bf16 bf16x8;
typedef __attribute__((ext_vector_type(4))) float f32x4;
typedef __attribute__((ext_vector_type(8))) unsigned short u16x8;
typedef __attribute__((ext_vector_type(4))) unsigned short u16x4;

static __device__ __forceinline__ unsigned short f2bf(float f) {
    union { float f; unsigned int u; } v; v.f = f;
    unsigned int u = v.u;
    return (unsigned short)((u + 0x7FFFu + ((u >> 16) & 1u)) >> 16);
}

// v_cvt_pk_bf16_f32: D[15:0]=bf16(lo), D[31:16]=bf16(hi), RNE
static __device__ __forceinline__ unsigned cvtpk(float lo, float hi) {
    unsigned r;
    asm("v_cvt_pk_bf16_f32 %0, %1, %2" : "=v"(r) : "v"(lo), "v"(hi));
    return r;
}

static __device__ __forceinline__ bf16x8 ldb8(const unsigned short* p) {
    return *reinterpret_cast<const bf16x8*>(p);
}

// async global->LDS DMA, 16B per lane; LDS dest = wave-uniform base + lane*16
static __device__ __forceinline__ void gload16(const unsigned short* g,
                                               unsigned short* l) {
    __builtin_amdgcn_global_load_lds(
        (const __attribute__((address_space(1))) unsigned int*)g,
        (__attribute__((address_space(3))) unsigned int*)l, 16, 0, 0);
}

// ---------------- 4-weight f32 -> bf16 conversion, one launch ----------------
__global__ __launch_bounds__(256) void convw4(const float4* __restrict__ a,
                                              const float4* __restrict__ b,
                                              const float4* __restrict__ c,
                                              const float4* __restrict__ d,
                                              u16x8* __restrict__ dst) {
    int i = blockIdx.x * 256 + threadIdx.x;  // 0..131071
    int sel = i >> 15;
    const float4* s = sel == 0 ? a : sel == 1 ? b : sel == 2 ? c : d;
    int j = i & 32767;
    float4 x = s[2 * j];
    float4 y = s[2 * j + 1];
    unsigned u0 = cvtpk(x.x, x.y), u1 = cvtpk(x.z, x.w);
    unsigned u2 = cvtpk(y.x, y.y), u3 = cvtpk(y.z, y.w);
    u16x8 o;
    o[0] = (unsigned short)u0; o[1] = (unsigned short)(u0 >> 16);
    o[2] = (unsigned short)u1; o[3] = (unsigned short)(u1 >> 16);
    o[4] = (unsigned short)u2; o[5] = (unsigned short)(u2 >> 16);
    o[6] = (unsigned short)u3; o[7] = (unsigned short)(u3 >> 16);
    dst[i] = o;
}

// ---------------- mask bit-pack: inc int32 (BS*E*N) -> u64 bitgroups ----------------
// 8 groups per wave, pipelined loads. 8192 blocks x 4 waves x 8 = 262144 groups.
__global__ __launch_bounds__(256) void maskpack(const int* __restrict__ inc,
                                                unsigned long long* __restrict__ mb) {
    int wid = blockIdx.x * 4 + (threadIdx.x >> 6);
    int lane = threadIdx.x & 63;
#pragma unroll
    for (int j = 0; j < 8; ++j) {
        int g = wid * 8 + j;
        int v = inc[(size_t)g * 64 + lane];
        unsigned long long m = __ballot(v != 0);
        if (lane == 0) mb[g] = m;
    }
}

// ---------------- NT GEMM: C[m][n] = (sum_k A[m][k]*W[n][k] + bias[n]) * oscale ----
template <int MODE, int NT, bool AF32>
__global__ __launch_bounds__(256) void gemm_nt(const void* __restrict__ Av,
                                               const unsigned short* __restrict__ W,
                                               const float* __restrict__ bias,
                                               void* __restrict__ Cout, float oscale) {
    const int K = DMODEL;
    int w = threadIdx.x >> 6, l = threadIdx.x & 63;
    int lr = l & 15, lh = l >> 4;
    int m0 = blockIdx.x * 64 + w * 16;
    int n0 = blockIdx.y * (NT * 16);

    f32x4 acc[NT] = {};

#pragma unroll 4
    for (int k0 = 0; k0 < K; k0 += 32) {
        bf16x8 a;
        if constexpr (AF32) {
            const float* Af = (const float*)Av + (size_t)(m0 + lr) * K + k0 + lh * 8;
            float4 x = *reinterpret_cast<const float4*>(Af);
            float4 y = *reinterpret_cast<const float4*>(Af + 4);
            unsigned u0 = cvtpk(x.x, x.y), u1 = cvtpk(x.z, x.w);
            unsigned u2 = cvtpk(y.x, y.y), u3 = cvtpk(y.z, y.w);
            u16x8 t8;
            t8[0] = (unsigned short)u0; t8[1] = (unsigned short)(u0 >> 16);
            t8[2] = (unsigned short)u1; t8[3] = (unsigned short)(u1 >> 16);
            t8[4] = (unsigned short)u2; t8[5] = (unsigned short)(u2 >> 16);
            t8[6] = (unsigned short)u3; t8[7] = (unsigned short)(u3 >> 16);
            a = __builtin_bit_cast(bf16x8, t8);
        } else {
            a = ldb8((const unsigned short*)Av + (size_t)(m0 + lr) * K + k0 + lh * 8);
        }
#pragma unroll
        for (int t = 0; t < NT; ++t) {
            bf16x8 b = ldb8(W + (size_t)(n0 + t * 16 + lr) * K + k0 + lh * 8);
            acc[t] = __builtin_amdgcn_mfma_f32_16x16x32_bf16(a, b, acc[t], 0, 0, 0);
        }
    }

    if constexpr (MODE == 0) {
        unsigned short* C = (unsigned short*)Cout;
#pragma unroll
        for (int t = 0; t < NT; ++t) {
            float bv = bias[n0 + t * 16 + lr];
#pragma unroll
            for (int r = 0; r < 4; ++r) {
                C[(size_t)(m0 + lh * 4 + r) * DMODEL + n0 + t * 16 + lr] =
                    f2bf((acc[t][r] + bv) * oscale);
            }
        }
    } else if constexpr (MODE == 1) {
        // rows of A are (b*4096 + node); cols are h*64 + d
        unsigned short* Vt = (unsigned short*)Cout;
        int bb = m0 >> 12;
        int node0 = (m0 & (NNODE - 1)) + lh * 4;
#pragma unroll
        for (int t = 0; t < NT; ++t) {
            int n = n0 + t * 16;
            int hh = n >> 6;
            int dd = (n & 63) + lr;
            float bv = bias[n + lr];
            u16x4 pk;
#pragma unroll
            for (int r = 0; r < 4; ++r) pk[r] = f2bf((acc[t][r] + bv) * oscale);
            *reinterpret_cast<u16x4*>(Vt + (size_t)((bb * NHEADS + hh) * DK + dd) * NNODE +
                                      node0) = pk;
        }
    } else {
        float* C = (float*)Cout;
#pragma unroll
        for (int t = 0; t < NT; ++t) {
            float bv = bias[n0 + t * 16 + lr];
#pragma unroll
            for (int r = 0; r < 4; ++r) {
                C[(size_t)(m0 + lh * 4 + r) * DMODEL + n0 + t * 16 + lr] =
                    (acc[t][r] + bv) * oscale;
            }
        }
    }
}

// ---------------- fused masked attention, LDS-staged 2-phase pipeline ------------
// Block = 64 edges (4 waves x 16), one (b,h) pair, ALL 4096 nodes in 64-node chunks.
// K/V chunks double-buffered in LDS via global_load_lds (async DMA, no VGPR cost),
// XOR-swizzled (write: pre-swizzled global source; read: same involution).
// Grid 512, XCD-swizzled: 4 (b,h) pairs per XCD -> K/V slices L2-resident.
__global__ __launch_bounds__(256) void attn_kernel(
    const unsigned short* __restrict__ Qb, const unsigned short* __restrict__ Kb,
    const unsigned short* __restrict__ Vt, const unsigned long long* __restrict__ mbits,
    unsigned short* __restrict__ Ob) {
    int w = threadIdx.x >> 6, l = threadIdx.x & 63;
    int lr = l & 15, lh = l >> 4;
    // id = xcd | (et<<3) | (ps<<7); pair = xcd*4+ps -> all 16 e-tiles of a pair on 1 XCD
    int id = blockIdx.x;
    int xcd = id & 7, et = (id >> 3) & 15, ps = id >> 7;
    int pair = xcd * 4 + ps;
    int b = pair >> 3, h = pair & 7;
    int e0 = et * 64 + w * 16;  // this wave's 16-edge base

    __shared__ unsigned short Kst[2][64][64];  // [buf][node][k]  8KB per buf, swizzled
    __shared__ unsigned short Vst[2][64][64];  // [buf][d][node]  8KB per buf, swizzled
    __shared__ unsigned short Pt[4][16][76];   // per-wave P tile (pad 76: conflict-free)
    unsigned short* Pw = &Pt[w][0][0];

    // Q fragments (A operand): row = lr, k = (0|32) + lh*8
    const unsigned short* Qrow = Qb + (size_t)(b * NE + e0 + lr) * DMODEL + h * DK;
    bf16x8 q0 = ldb8(Qrow + lh * 8);
    bf16x8 q1 = ldb8(Qrow + 32 + lh * 8);

    const unsigned short* Kg = Kb + (size_t)b * NNODE * DMODEL + h * DK;
    const unsigned short* Vg = Vt + (size_t)((b * NHEADS + h) * DK) * NNODE;
    const unsigned long long* mrow = mbits + (size_t)(b * NE + e0) * 64;

    // staging geometry: wave w stages rows w*16+ii*8+(l>>3); 16B-unit col = l&7
    int srow0 = w * 16 + (l >> 3);
    int scol = l & 7;

    f32x4 oacc[4] = {};
    float lsum[4] = {0.f, 0.f, 0.f, 0.f};

    auto stage = [&](int bf, int cb) {
#pragma unroll
        for (int ii = 0; ii < 2; ++ii) {
            int row = srow0 + ii * 8;
            int cu = scol ^ (row & 7);  // pre-swizzled global source (rule #21)
            gload16(Kg + (size_t)(cb * 64 + row) * DMODEL + cu * 8,
                    &Kst[bf][w * 16 + ii * 8][0]);
            gload16(Vg + (size_t)row * NNODE + cb * 64 + cu * 8,
                    &Vst[bf][w * 16 + ii * 8][0]);
        }
    };

    unsigned long long mcur[4], mnext[4];

    stage(0, 0);
#pragma unroll
    for (int r = 0; r < 4; ++r) mcur[r] = mrow[(lh * 4 + r) * 64];
    __syncthreads();

    int bf = 0;
    for (int cb = 0; cb < 64; ++cb) {
        if (cb < 63) {
            stage(bf ^ 1, cb + 1);  // async into other buffer, drains at the barrier
#pragma unroll
            for (int r = 0; r < 4; ++r) mnext[r] = mrow[(lh * 4 + r) * 64 + cb + 1];
        }
        // ---- K fragments (swizzled read) + QK^T ----
        bf16x8 kf[4][2];
#pragma unroll
        for (int t = 0; t < 4; ++t) {
            int row = t * 16 + lr;
            kf[t][0] = ldb8(&Kst[bf][row][((0 + lh) ^ (lr & 7)) * 8]);
            kf[t][1] = ldb8(&Kst[bf][row][((4 + lh) ^ (lr & 7)) * 8]);
        }
        f32x4 s[4] = {};
#pragma unroll
        for (int t = 0; t < 4; ++t) {
            s[t] = __builtin_amdgcn_mfma_f32_16x16x32_bf16(q0, kf[t][0], s[t], 0, 0, 0);
            s[t] = __builtin_amdgcn_mfma_f32_16x16x32_bf16(q1, kf[t][1], s[t], 0, 0, 0);
        }
        // ---- V fragments issued now, in flight during softmax ----
        bf16x8 vf[2][4];
#pragma unroll
        for (int kk = 0; kk < 2; ++kk)
#pragma unroll
            for (int dt = 0; dt < 4; ++dt) {
                int row = dt * 16 + lr;
                vf[kk][dt] = ldb8(&Vst[bf][row][((kk * 4 + lh) ^ (lr & 7)) * 8]);
            }
        // ---- p = maskbit * exp(s); accumulate l; pack P to LDS ----
#pragma unroll
        for (int t = 0; t < 4; ++t) {
#pragma unroll
            for (int r = 0; r < 4; ++r) {
                float p = __expf(s[t][r]);
                unsigned half = (t < 2) ? (unsigned)mcur[r] : (unsigned)(mcur[r] >> 32);
                unsigned bits = half >> ((t & 1) * 16 + lr);
                p = (bits & 1u) ? p : 0.0f;
                s[t][r] = p;
                lsum[r] += p;
            }
            unsigned p01 = cvtpk(s[t][0], s[t][1]);
            unsigned p23 = cvtpk(s[t][2], s[t][3]);
            Pw[(lh * 4 + 0) * 76 + t * 16 + lr] = (unsigned short)p01;
            Pw[(lh * 4 + 1) * 76 + t * 16 + lr] = (unsigned short)(p01 >> 16);
            Pw[(lh * 4 + 2) * 76 + t * 16 + lr] = (unsigned short)p23;
            Pw[(lh * 4 + 3) * 76 + t * 16 + lr] = (unsigned short)(p23 >> 16);
        }
        // ---- O += P @ V ----
#pragma unroll
        for (int kk = 0; kk < 2; ++kk) {
            bf16x8 pa = ldb8(Pw + lr * 76 + kk * 32 + lh * 8);
#pragma unroll
            for (int dt = 0; dt < 4; ++dt) {
                oacc[dt] = __builtin_amdgcn_mfma_f32_16x16x32_bf16(pa, vf[kk][dt],
                                                                   oacc[dt], 0, 0, 0);
            }
        }
        __syncthreads();  // implicit vmcnt(0): next buffer staged; this buffer free
        bf ^= 1;
#pragma unroll
        for (int r = 0; r < 4; ++r) mcur[r] = mnext[r];
    }

    // ---- epilogue: reduce l over the 16 node-lanes, write O directly ----
#pragma unroll
    for (int r = 0; r < 4; ++r) {
        float v = lsum[r];
        v += __shfl_xor(v, 1);
        v += __shfl_xor(v, 2);
        v += __shfl_xor(v, 4);
        v += __shfl_xor(v, 8);
        lsum[r] = v;
    }
#pragma unroll
    for (int r = 0; r < 4; ++r) {
        float inv = 1.0f / lsum[r];
        size_t row = (size_t)(b * NE + e0 + lh * 4 + r) * DMODEL + h * DK;
#pragma unroll
        for (int dt = 0; dt < 4; ++dt) {
            Ob[row + dt * 16 + lr] = f2bf(oacc[dt][r] * inv);
        }
    }
}

// ---------------- launch ----------------
extern "C" void kernel_launch(void* const* d_in, const int* in_sizes, int n_in,
                              void* d_out, int out_size, void* d_ws, size_t ws_size,
                              hipStream_t stream) {
    const float* queries = (const float*)d_in[0];
    const float* keys = (const float*)d_in[1];
    const int* inc = (const int*)d_in[2];
    const float* Wq = (const float*)d_in[3];
    const float* bq = (const float*)d_in[4];
    const float* Wk = (const float*)d_in[5];
    const float* bk = (const float*)d_in[6];
    const float* Wv = (const float*)d_in[7];
    const float* bv = (const float*)d_in[8];
    const float* Wo = (const float*)d_in[9];
    const float* bo = (const float*)d_in[10];

    unsigned long long* mbits = (unsigned long long*)d_ws;          // 262144 u64 = 2 MB
    unsigned short* wqb = (unsigned short*)(mbits + BSZ * NE * 64); // 4 x 512*512 bf16
    unsigned short* wkb = wqb + DMODEL * DMODEL;
    unsigned short* wvb = wkb + DMODEL * DMODEL;
    unsigned short* wob = wvb + DMODEL * DMODEL;
    unsigned short* Qb = wob + DMODEL * DMODEL;                     // BS*E*512
    unsigned short* Kb = Qb + (size_t)BSZ * NE * DMODEL;            // BS*N*512
    unsigned short* Vt = Kb + (size_t)BSZ * NNODE * DMODEL;         // BS*8*64 x 4096
    unsigned short* Ob = Vt + (size_t)BSZ * NNODE * DMODEL;         // BS*E*512

    convw4<<<512, 256, 0, stream>>>((const float4*)Wq, (const float4*)Wk,
                                    (const float4*)Wv, (const float4*)Wo, (u16x8*)wqb);
    maskpack<<<8192, 256, 0, stream>>>(inc, mbits);

    // Q projection pre-scaled by 1/sqrt(d_k) = 1/8
    gemm_nt<0, 4, true><<<dim3(BSZ * NE / 64, 8), 256, 0, stream>>>(queries, wqb, bq, Qb,
                                                                    0.125f);
    gemm_nt<0, 16, true><<<dim3(BSZ * NNODE / 64, 2), 256, 0, stream>>>(keys, wkb, bk, Kb,
                                                                        1.0f);
    gemm_nt<1, 16, true><<<dim3(BSZ * NNODE / 64, 2), 256, 0, stream>>>(keys, wvb, bv, Vt,
                                                                        1.0f);

    attn_kernel<<<dim3(512), 256, 0, stream>>>(Qb, Kb, Vt, mbits, Ob);

    gemm_nt<2, 4, false><<<dim3(BSZ * NE / 64, 8), 256, 0, stream>>>(Ob, wob, bo, d_out,
                                                                     1.0f);
}

// Round 6
// 328.486 us; speedup vs baseline: 1.9205x; 1.4273x over previous
//
#include <hip/hip_runtime.h>

#define DMODEL 512
#define NHEADS 8
#define DK 64
#define BSZ 4
#define NE 1024
#define NNODE 4096

typedef __attribute__((ext_vector_type(8))) __bf16 bf16x8;
typedef __attribute__((ext_vector_type(4))) float f32x4;
typedef __attribute__((ext_vector_type(8))) unsigned short u16x8;
typedef __attribute__((ext_vector_type(4))) unsigned short u16x4;

static __device__ __forceinline__ unsigned short f2bf(float f) {
    union { float f; unsigned int u; } v; v.f = f;
    unsigned int u = v.u;
    return (unsigned short)((u + 0x7FFFu + ((u >> 16) & 1u)) >> 16);
}

// v_cvt_pk_bf16_f32: D[15:0]=bf16(lo), D[31:16]=bf16(hi), RNE
static __device__ __forceinline__ unsigned cvtpk(float lo, float hi) {
    unsigned r;
    asm("v_cvt_pk_bf16_f32 %0, %1, %2" : "=v"(r) : "v"(lo), "v"(hi));
    return r;
}

static __device__ __forceinline__ bf16x8 ldb8(const unsigned short* p) {
    return *reinterpret_cast<const bf16x8*>(p);
}

// async global->LDS DMA, 16B per lane; LDS dest = wave-uniform base + lane*16
static __device__ __forceinline__ void gload16(const unsigned short* g,
                                               unsigned short* l) {
    __builtin_amdgcn_global_load_lds(
        (const __attribute__((address_space(1))) unsigned int*)g,
        (__attribute__((address_space(3))) unsigned int*)l, 16, 0, 0);
}

// ---------------- f32 -> bf16 conversion (8 elems/thread) ----------------
__global__ __launch_bounds__(256) void convk(const float4* __restrict__ src,
                                             u16x8* __restrict__ dst) {
    int i = blockIdx.x * 256 + threadIdx.x;
    float4 a = src[2 * i];
    float4 b = src[2 * i + 1];
    unsigned u0 = cvtpk(a.x, a.y), u1 = cvtpk(a.z, a.w);
    unsigned u2 = cvtpk(b.x, b.y), u3 = cvtpk(b.z, b.w);
    u16x8 o;
    o[0] = (unsigned short)u0; o[1] = (unsigned short)(u0 >> 16);
    o[2] = (unsigned short)u1; o[3] = (unsigned short)(u1 >> 16);
    o[4] = (unsigned short)u2; o[5] = (unsigned short)(u2 >> 16);
    o[6] = (unsigned short)u3; o[7] = (unsigned short)(u3 >> 16);
    dst[i] = o;
}

// ---------------- 4-weight f32 -> bf16 conversion, one launch ----------------
__global__ __launch_bounds__(256) void convw4(const float4* __restrict__ a,
                                              const float4* __restrict__ b,
                                              const float4* __restrict__ c,
                                              const float4* __restrict__ d,
                                              u16x8* __restrict__ dst) {
    int i = blockIdx.x * 256 + threadIdx.x;  // 0..131071
    int sel = i >> 15;
    const float4* s = sel == 0 ? a : sel == 1 ? b : sel == 2 ? c : d;
    int j = i & 32767;
    float4 x = s[2 * j];
    float4 y = s[2 * j + 1];
    unsigned u0 = cvtpk(x.x, x.y), u1 = cvtpk(x.z, x.w);
    unsigned u2 = cvtpk(y.x, y.y), u3 = cvtpk(y.z, y.w);
    u16x8 o;
    o[0] = (unsigned short)u0; o[1] = (unsigned short)(u0 >> 16);
    o[2] = (unsigned short)u1; o[3] = (unsigned short)(u1 >> 16);
    o[4] = (unsigned short)u2; o[5] = (unsigned short)(u2 >> 16);
    o[6] = (unsigned short)u3; o[7] = (unsigned short)(u3 >> 16);
    dst[i] = o;
}

// ---------------- mask bit-pack: inc int32 (BS*E*N) -> u64 bitgroups ----------------
__global__ __launch_bounds__(256) void maskpack(const int* __restrict__ inc,
                                                unsigned long long* __restrict__ mb) {
    int wid = blockIdx.x * 4 + (threadIdx.x >> 6);
    int lane = threadIdx.x & 63;
#pragma unroll
    for (int j = 0; j < 8; ++j) {
        int g = wid * 8 + j;
        int v = inc[(size_t)g * 64 + lane];
        unsigned long long m = __ballot(v != 0);
        if (lane == 0) mb[g] = m;
    }
}

// ---------------- LDS-staged NT GEMM (m97 structure, 2-phase pipeline) ------------
// C[m][n] = (sum_k A[m][k]*W[n][k] + bias[n]) * oscale.  A: Mx512 bf16, W: 512x512
// bf16, both row-major in K. Tile 128x128, BK=64, 4 waves (2x2), 4x4 frags/wave.
// A/B double-buffered in LDS via global_load_lds, XOR-swizzled both sides (rule #21).
// MODE 0: bf16 row-major out; MODE 1: transposed V-layout; MODE 2: f32 out.
template <int MODE>
__global__ __launch_bounds__(256) void gemm128(const unsigned short* __restrict__ A,
                                               const unsigned short* __restrict__ W,
                                               const float* __restrict__ bias,
                                               void* __restrict__ Cout, float oscale) {
    int w = threadIdx.x >> 6, l = threadIdx.x & 63;
    int lr = l & 15, lh = l >> 4;
    int wm = w >> 1, wn = w & 1;
    int m0 = blockIdx.x * 128, n0 = blockIdx.y * 128;

    __shared__ unsigned short Ast[2][128][64];  // 16 KB per buf, swizzled
    __shared__ unsigned short Bst[2][128][64];

    int srow = w * 32 + (l >> 3);  // + ii*8; wave covers rows [w*32, w*32+32)
    int scu = l & 7;

    auto stage = [&](int bf, int k0) {
#pragma unroll
        for (int ii = 0; ii < 4; ++ii) {
            int row = srow + ii * 8;
            int cu = scu ^ (row & 7);  // pre-swizzled global source
            gload16(A + (size_t)(m0 + row) * DMODEL + k0 + cu * 8,
                    &Ast[bf][w * 32 + ii * 8][0]);
            gload16(W + (size_t)(n0 + row) * DMODEL + k0 + cu * 8,
                    &Bst[bf][w * 32 + ii * 8][0]);
        }
    };

    f32x4 acc[4][4] = {};

    stage(0, 0);
    __syncthreads();

    int bf = 0;
    for (int t = 0; t < 8; ++t) {
        if (t < 7) stage(bf ^ 1, (t + 1) * 64);
#pragma unroll
        for (int half = 0; half < 2; ++half) {
            bf16x8 af[4], bfr[4];
#pragma unroll
            for (int mf = 0; mf < 4; ++mf)
                af[mf] = ldb8(&Ast[bf][wm * 64 + mf * 16 + lr]
                                  [((half * 4 + lh) ^ (lr & 7)) * 8]);
#pragma unroll
            for (int nf = 0; nf < 4; ++nf)
                bfr[nf] = ldb8(&Bst[bf][wn * 64 + nf * 16 + lr]
                                   [((half * 4 + lh) ^ (lr & 7)) * 8]);
#pragma unroll
            for (int mf = 0; mf < 4; ++mf)
#pragma unroll
                for (int nf = 0; nf < 4; ++nf)
                    acc[mf][nf] = __builtin_amdgcn_mfma_f32_16x16x32_bf16(
                        af[mf], bfr[nf], acc[mf][nf], 0, 0, 0);
        }
        __syncthreads();  // drains stage vmcnt; guards buffer reuse
        bf ^= 1;
    }

    if constexpr (MODE == 0) {
        unsigned short* C = (unsigned short*)Cout;
#pragma unroll
        for (int nf = 0; nf < 4; ++nf) {
            int ncol = n0 + wn * 64 + nf * 16 + lr;
            float bv = bias[ncol];
#pragma unroll
            for (int mf = 0; mf < 4; ++mf)
#pragma unroll
                for (int r = 0; r < 4; ++r)
                    C[(size_t)(m0 + wm * 64 + mf * 16 + lh * 4 + r) * DMODEL + ncol] =
                        f2bf((acc[mf][nf][r] + bv) * oscale);
        }
    } else if constexpr (MODE == 1) {
        // rows m = b*4096 + node; cols n = h*64 + d.  Vt[(b*8+h)*64+d][node]
        unsigned short* Vt = (unsigned short*)Cout;
        int bb = m0 >> 12;
        int nodebase = (m0 & (NNODE - 1)) + wm * 64;
#pragma unroll
        for (int nf = 0; nf < 4; ++nf) {
            int ncol = n0 + wn * 64 + nf * 16;
            int hh = ncol >> 6;
            int dd = (ncol & 63) + lr;
            float bv = bias[ncol + lr];
#pragma unroll
            for (int mf = 0; mf < 4; ++mf) {
                u16x4 pk;
#pragma unroll
                for (int r = 0; r < 4; ++r) pk[r] = f2bf(acc[mf][nf][r] + bv);
                int node0 = nodebase + mf * 16 + lh * 4;
                *reinterpret_cast<u16x4*>(
                    Vt + (size_t)((bb * NHEADS + hh) * DK + dd) * NNODE + node0) = pk;
            }
        }
    } else {
        float* C = (float*)Cout;
#pragma unroll
        for (int nf = 0; nf < 4; ++nf) {
            int ncol = n0 + wn * 64 + nf * 16 + lr;
            float bv = bias[ncol];
#pragma unroll
            for (int mf = 0; mf < 4; ++mf)
#pragma unroll
                for (int r = 0; r < 4; ++r)
                    C[(size_t)(m0 + wm * 64 + mf * 16 + lh * 4 + r) * DMODEL + ncol] =
                        acc[mf][nf][r] + bv;
        }
    }
}

// ---------------- fused masked attention, LDS-staged 2-phase pipeline ------------
// (unchanged from R5: 118 us, zero bank conflicts)
__global__ __launch_bounds__(256) void attn_kernel(
    const unsigned short* __restrict__ Qb, const unsigned short* __restrict__ Kb,
    const unsigned short* __restrict__ Vt, const unsigned long long* __restrict__ mbits,
    unsigned short* __restrict__ Ob) {
    int w = threadIdx.x >> 6, l = threadIdx.x & 63;
    int lr = l & 15, lh = l >> 4;
    int id = blockIdx.x;
    int xcd = id & 7, et = (id >> 3) & 15, ps = id >> 7;
    int pair = xcd * 4 + ps;
    int b = pair >> 3, h = pair & 7;
    int e0 = et * 64 + w * 16;

    __shared__ unsigned short Kst[2][64][64];
    __shared__ unsigned short Vst[2][64][64];
    __shared__ unsigned short Pt[4][16][76];
    unsigned short* Pw = &Pt[w][0][0];

    const unsigned short* Qrow = Qb + (size_t)(b * NE + e0 + lr) * DMODEL + h * DK;
    bf16x8 q0 = ldb8(Qrow + lh * 8);
    bf16x8 q1 = ldb8(Qrow + 32 + lh * 8);

    const unsigned short* Kg = Kb + (size_t)b * NNODE * DMODEL + h * DK;
    const unsigned short* Vg = Vt + (size_t)((b * NHEADS + h) * DK) * NNODE;
    const unsigned long long* mrow = mbits + (size_t)(b * NE + e0) * 64;

    int srow0 = w * 16 + (l >> 3);
    int scol = l & 7;

    f32x4 oacc[4] = {};
    float lsum[4] = {0.f, 0.f, 0.f, 0.f};

    auto stage = [&](int bf, int cb) {
#pragma unroll
        for (int ii = 0; ii < 2; ++ii) {
            int row = srow0 + ii * 8;
            int cu = scol ^ (row & 7);
            gload16(Kg + (size_t)(cb * 64 + row) * DMODEL + cu * 8,
                    &Kst[bf][w * 16 + ii * 8][0]);
            gload16(Vg + (size_t)row * NNODE + cb * 64 + cu * 8,
                    &Vst[bf][w * 16 + ii * 8][0]);
        }
    };

    unsigned long long mcur[4], mnext[4];

    stage(0, 0);
#pragma unroll
    for (int r = 0; r < 4; ++r) mcur[r] = mrow[(lh * 4 + r) * 64];
    __syncthreads();

    int bf = 0;
    for (int cb = 0; cb < 64; ++cb) {
        if (cb < 63) {
            stage(bf ^ 1, cb + 1);
#pragma unroll
            for (int r = 0; r < 4; ++r) mnext[r] = mrow[(lh * 4 + r) * 64 + cb + 1];
        }
        bf16x8 kf[4][2];
#pragma unroll
        for (int t = 0; t < 4; ++t) {
            int row = t * 16 + lr;
            kf[t][0] = ldb8(&Kst[bf][row][((0 + lh) ^ (lr & 7)) * 8]);
            kf[t][1] = ldb8(&Kst[bf][row][((4 + lh) ^ (lr & 7)) * 8]);
        }
        f32x4 s[4] = {};
#pragma unroll
        for (int t = 0; t < 4; ++t) {
            s[t] = __builtin_amdgcn_mfma_f32_16x16x32_bf16(q0, kf[t][0], s[t], 0, 0, 0);
            s[t] = __builtin_amdgcn_mfma_f32_16x16x32_bf16(q1, kf[t][1], s[t], 0, 0, 0);
        }
        bf16x8 vf[2][4];
#pragma unroll
        for (int kk = 0; kk < 2; ++kk)
#pragma unroll
            for (int dt = 0; dt < 4; ++dt) {
                int row = dt * 16 + lr;
                vf[kk][dt] = ldb8(&Vst[bf][row][((kk * 4 + lh) ^ (lr & 7)) * 8]);
            }
#pragma unroll
        for (int t = 0; t < 4; ++t) {
#pragma unroll
            for (int r = 0; r < 4; ++r) {
                float p = __expf(s[t][r]);
                unsigned half = (t < 2) ? (unsigned)mcur[r] : (unsigned)(mcur[r] >> 32);
                unsigned bits = half >> ((t & 1) * 16 + lr);
                p = (bits & 1u) ? p : 0.0f;
                s[t][r] = p;
                lsum[r] += p;
            }
            unsigned p01 = cvtpk(s[t][0], s[t][1]);
            unsigned p23 = cvtpk(s[t][2], s[t][3]);
            Pw[(lh * 4 + 0) * 76 + t * 16 + lr] = (unsigned short)p01;
            Pw[(lh * 4 + 1) * 76 + t * 16 + lr] = (unsigned short)(p01 >> 16);
            Pw[(lh * 4 + 2) * 76 + t * 16 + lr] = (unsigned short)p23;
            Pw[(lh * 4 + 3) * 76 + t * 16 + lr] = (unsigned short)(p23 >> 16);
        }
#pragma unroll
        for (int kk = 0; kk < 2; ++kk) {
            bf16x8 pa = ldb8(Pw + lr * 76 + kk * 32 + lh * 8);
#pragma unroll
            for (int dt = 0; dt < 4; ++dt) {
                oacc[dt] = __builtin_amdgcn_mfma_f32_16x16x32_bf16(pa, vf[kk][dt],
                                                                   oacc[dt], 0, 0, 0);
            }
        }
        __syncthreads();
        bf ^= 1;
#pragma unroll
        for (int r = 0; r < 4; ++r) mcur[r] = mnext[r];
    }

#pragma unroll
    for (int r = 0; r < 4; ++r) {
        float v = lsum[r];
        v += __shfl_xor(v, 1);
        v += __shfl_xor(v, 2);
        v += __shfl_xor(v, 4);
        v += __shfl_xor(v, 8);
        lsum[r] = v;
    }
#pragma unroll
    for (int r = 0; r < 4; ++r) {
        float inv = 1.0f / lsum[r];
        size_t row = (size_t)(b * NE + e0 + lh * 4 + r) * DMODEL + h * DK;
#pragma unroll
        for (int dt = 0; dt < 4; ++dt) {
            Ob[row + dt * 16 + lr] = f2bf(oacc[dt][r] * inv);
        }
    }
}

// ---------------- launch ----------------
extern "C" void kernel_launch(void* const* d_in, const int* in_sizes, int n_in,
                              void* d_out, int out_size, void* d_ws, size_t ws_size,
                              hipStream_t stream) {
    const float* queries = (const float*)d_in[0];
    const float* keys = (const float*)d_in[1];
    const int* inc = (const int*)d_in[2];
    const float* Wq = (const float*)d_in[3];
    const float* bq = (const float*)d_in[4];
    const float* Wk = (const float*)d_in[5];
    const float* bk = (const float*)d_in[6];
    const float* Wv = (const float*)d_in[7];
    const float* bv = (const float*)d_in[8];
    const float* Wo = (const float*)d_in[9];
    const float* bo = (const float*)d_in[10];

    unsigned long long* mbits = (unsigned long long*)d_ws;          // 2 MB
    unsigned short* wqb = (unsigned short*)(mbits + BSZ * NE * 64); // 4 x 512KB bf16
    unsigned short* wkb = wqb + DMODEL * DMODEL;
    unsigned short* wvb = wkb + DMODEL * DMODEL;
    unsigned short* wob = wvb + DMODEL * DMODEL;
    unsigned short* qbf = wob + DMODEL * DMODEL;                    // BS*E*512  (4 MB)
    unsigned short* kbf = qbf + (size_t)BSZ * NE * DMODEL;          // BS*N*512 (16 MB)
    unsigned short* Qb = kbf + (size_t)BSZ * NNODE * DMODEL;        // 4 MB
    unsigned short* Kb = Qb + (size_t)BSZ * NE * DMODEL;            // 16 MB
    unsigned short* Vt = Kb + (size_t)BSZ * NNODE * DMODEL;         // 16 MB
    unsigned short* Ob = Vt + (size_t)BSZ * NNODE * DMODEL;         // 4 MB

    convk<<<BSZ * NE * DMODEL / 8 / 256, 256, 0, stream>>>((const float4*)queries,
                                                           (u16x8*)qbf);
    convk<<<BSZ * NNODE * DMODEL / 8 / 256, 256, 0, stream>>>((const float4*)keys,
                                                              (u16x8*)kbf);
    convw4<<<512, 256, 0, stream>>>((const float4*)Wq, (const float4*)Wk,
                                    (const float4*)Wv, (const float4*)Wo, (u16x8*)wqb);
    maskpack<<<8192, 256, 0, stream>>>(inc, mbits);

    // Q projection pre-scaled by 1/sqrt(d_k) = 1/8
    gemm128<0><<<dim3(BSZ * NE / 128, 4), 256, 0, stream>>>(qbf, wqb, bq, Qb, 0.125f);
    gemm128<0><<<dim3(BSZ * NNODE / 128, 4), 256, 0, stream>>>(kbf, wkb, bk, Kb, 1.0f);
    gemm128<1><<<dim3(BSZ * NNODE / 128, 4), 256, 0, stream>>>(kbf, wvb, bv, Vt, 1.0f);

    attn_kernel<<<dim3(512), 256, 0, stream>>>(Qb, Kb, Vt, mbits, Ob);

    gemm128<2><<<dim3(BSZ * NE / 128, 4), 256, 0, stream>>>(Ob, wob, bo, d_out, 1.0f);
}

// Round 7
// 323.095 us; speedup vs baseline: 1.9526x; 1.0167x over previous
//
#include <hip/hip_runtime.h>

#define DMODEL 512
#define NHEADS 8
#define DK 64
#define BSZ 4
#define NE 1024
#define NNODE 4096

typedef __attribute__((ext_vector_type(8))) __bf16 bf16x8;
typedef __attribute__((ext_vector_type(4))) float f32x4;
typedef __attribute__((ext_vector_type(8))) unsigned short u16x8;
typedef __attribute__((ext_vector_type(4))) unsigned short u16x4;

static __device__ __forceinline__ unsigned short f2bf(float f) {
    union { float f; unsigned int u; } v; v.f = f;
    unsigned int u = v.u;
    return (unsigned short)((u + 0x7FFFu + ((u >> 16) & 1u)) >> 16);
}

// v_cvt_pk_bf16_f32: D[15:0]=bf16(lo), D[31:16]=bf16(hi), RNE
static __device__ __forceinline__ unsigned cvtpk(float lo, float hi) {
    unsigned r;
    asm("v_cvt_pk_bf16_f32 %0, %1, %2" : "=v"(r) : "v"(lo), "v"(hi));
    return r;
}

// raw v_exp_f32: 2^x (inputs pre-scaled to log2 domain)
static __device__ __forceinline__ float exp2v(float x) {
    float r;
    asm("v_exp_f32 %0, %1" : "=v"(r) : "v"(x));
    return r;
}

static __device__ __forceinline__ bf16x8 ldb8(const unsigned short* p) {
    return *reinterpret_cast<const bf16x8*>(p);
}

// async global->LDS DMA, 16B per lane; LDS dest = wave-uniform base + lane*16
static __device__ __forceinline__ void gload16(const unsigned short* g,
                                               unsigned short* l) {
    __builtin_amdgcn_global_load_lds(
        (const __attribute__((address_space(1))) unsigned int*)g,
        (__attribute__((address_space(3))) unsigned int*)l, 16, 0, 0);
}

// ---------------- merged f32 -> bf16 conversion: queries | keys | 4 weights -------
// 262144 + 1048576 + 131072 = 1441792 groups of 8 elems; grid 5632 x 256.
__global__ __launch_bounds__(256) void conv_all(
    const float4* __restrict__ q, const float4* __restrict__ k,
    const float4* __restrict__ wq, const float4* __restrict__ wk,
    const float4* __restrict__ wv, const float4* __restrict__ wo,
    u16x8* __restrict__ qb, u16x8* __restrict__ kb, u16x8* __restrict__ wb) {
    int i = blockIdx.x * 256 + threadIdx.x;
    const float4* s;
    u16x8* d;
    int j;
    if (i < 262144) {
        s = q; d = qb; j = i;
    } else if (i < 1310720) {
        s = k; d = kb; j = i - 262144;
    } else {
        int t = i - 1310720;
        int sel = t >> 15;
        s = sel == 0 ? wq : sel == 1 ? wk : sel == 2 ? wv : wo;
        d = wb + ((size_t)sel << 15);
        j = t & 32767;
    }
    float4 x = s[2 * j];
    float4 y = s[2 * j + 1];
    unsigned u0 = cvtpk(x.x, x.y), u1 = cvtpk(x.z, x.w);
    unsigned u2 = cvtpk(y.x, y.y), u3 = cvtpk(y.z, y.w);
    u16x8 o;
    o[0] = (unsigned short)u0; o[1] = (unsigned short)(u0 >> 16);
    o[2] = (unsigned short)u1; o[3] = (unsigned short)(u1 >> 16);
    o[4] = (unsigned short)u2; o[5] = (unsigned short)(u2 >> 16);
    o[6] = (unsigned short)u3; o[7] = (unsigned short)(u3 >> 16);
    d[j] = o;
}

// ---------------- mask bit-pack: inc int32 (BS*E*N) -> u64 bitgroups ----------------
__global__ __launch_bounds__(256) void maskpack(const int* __restrict__ inc,
                                                unsigned long long* __restrict__ mb) {
    int wid = blockIdx.x * 4 + (threadIdx.x >> 6);
    int lane = threadIdx.x & 63;
#pragma unroll
    for (int j = 0; j < 8; ++j) {
        int g = wid * 8 + j;
        int v = inc[(size_t)g * 64 + lane];
        unsigned long long m = __ballot(v != 0);
        if (lane == 0) mb[g] = m;
    }
}

// ---------------- LDS-staged NT GEMM (m97 structure, 2-phase pipeline) ------------
template <int MODE>
__global__ __launch_bounds__(256) void gemm128(const unsigned short* __restrict__ A,
                                               const unsigned short* __restrict__ W,
                                               const float* __restrict__ bias,
                                               void* __restrict__ Cout, float oscale) {
    int w = threadIdx.x >> 6, l = threadIdx.x & 63;
    int lr = l & 15, lh = l >> 4;
    int wm = w >> 1, wn = w & 1;
    int m0 = blockIdx.x * 128, n0 = blockIdx.y * 128;

    __shared__ unsigned short Ast[2][128][64];
    __shared__ unsigned short Bst[2][128][64];

    int srow = w * 32 + (l >> 3);
    int scu = l & 7;

    auto stage = [&](int bf, int k0) {
#pragma unroll
        for (int ii = 0; ii < 4; ++ii) {
            int row = srow + ii * 8;
            int cu = scu ^ (row & 7);
            gload16(A + (size_t)(m0 + row) * DMODEL + k0 + cu * 8,
                    &Ast[bf][w * 32 + ii * 8][0]);
            gload16(W + (size_t)(n0 + row) * DMODEL + k0 + cu * 8,
                    &Bst[bf][w * 32 + ii * 8][0]);
        }
    };

    f32x4 acc[4][4] = {};

    stage(0, 0);
    __syncthreads();

    int bf = 0;
    for (int t = 0; t < 8; ++t) {
        if (t < 7) stage(bf ^ 1, (t + 1) * 64);
#pragma unroll
        for (int half = 0; half < 2; ++half) {
            bf16x8 af[4], bfr[4];
#pragma unroll
            for (int mf = 0; mf < 4; ++mf)
                af[mf] = ldb8(&Ast[bf][wm * 64 + mf * 16 + lr]
                                  [((half * 4 + lh) ^ (lr & 7)) * 8]);
#pragma unroll
            for (int nf = 0; nf < 4; ++nf)
                bfr[nf] = ldb8(&Bst[bf][wn * 64 + nf * 16 + lr]
                                   [((half * 4 + lh) ^ (lr & 7)) * 8]);
#pragma unroll
            for (int mf = 0; mf < 4; ++mf)
#pragma unroll
                for (int nf = 0; nf < 4; ++nf)
                    acc[mf][nf] = __builtin_amdgcn_mfma_f32_16x16x32_bf16(
                        af[mf], bfr[nf], acc[mf][nf], 0, 0, 0);
        }
        __syncthreads();
        bf ^= 1;
    }

    if constexpr (MODE == 0) {
        unsigned short* C = (unsigned short*)Cout;
#pragma unroll
        for (int nf = 0; nf < 4; ++nf) {
            int ncol = n0 + wn * 64 + nf * 16 + lr;
            float bv = bias[ncol];
#pragma unroll
            for (int mf = 0; mf < 4; ++mf)
#pragma unroll
                for (int r = 0; r < 4; ++r)
                    C[(size_t)(m0 + wm * 64 + mf * 16 + lh * 4 + r) * DMODEL + ncol] =
                        f2bf((acc[mf][nf][r] + bv) * oscale);
        }
    } else if constexpr (MODE == 1) {
        unsigned short* Vt = (unsigned short*)Cout;
        int bb = m0 >> 12;
        int nodebase = (m0 & (NNODE - 1)) + wm * 64;
#pragma unroll
        for (int nf = 0; nf < 4; ++nf) {
            int ncol = n0 + wn * 64 + nf * 16;
            int hh = ncol >> 6;
            int dd = (ncol & 63) + lr;
            float bv = bias[ncol + lr];
#pragma unroll
            for (int mf = 0; mf < 4; ++mf) {
                u16x4 pk;
#pragma unroll
                for (int r = 0; r < 4; ++r) pk[r] = f2bf(acc[mf][nf][r] + bv);
                int node0 = nodebase + mf * 16 + lh * 4;
                *reinterpret_cast<u16x4*>(
                    Vt + (size_t)((bb * NHEADS + hh) * DK + dd) * NNODE + node0) = pk;
            }
        }
    } else {
        float* C = (float*)Cout;
#pragma unroll
        for (int nf = 0; nf < 4; ++nf) {
            int ncol = n0 + wn * 64 + nf * 16 + lr;
            float bv = bias[ncol];
#pragma unroll
            for (int mf = 0; mf < 4; ++mf)
#pragma unroll
                for (int r = 0; r < 4; ++r)
                    C[(size_t)(m0 + wm * 64 + mf * 16 + lh * 4 + r) * DMODEL + ncol] =
                        acc[mf][nf][r] + bv;
        }
    }
}

// ---------------- fused masked attention, node-split x2, LDS-staged pipeline ------
// Grid 1024 (3 blocks/CU resident, 12 waves/CU). Block = (b,h) pair, 64 edges,
// node segment seg*2048..+2048 in 32 chunks of 64. Qb pre-scaled by log2e/8 so
// softmax is raw v_exp_f32 (2^x). Outputs UNNORMALIZED partial O (f32) + partial
// lsum; combine2 kernel finishes (O0+O1)/(L0+L1).
__global__ __launch_bounds__(256) void attn_kernel(
    const unsigned short* __restrict__ Qb, const unsigned short* __restrict__ Kb,
    const unsigned short* __restrict__ Vt, const unsigned long long* __restrict__ mbits,
    float* __restrict__ Op, float* __restrict__ Lp) {
    int w = threadIdx.x >> 6, l = threadIdx.x & 63;
    int lr = l & 15, lh = l >> 4;
    // id = xcd | (et<<3) | (ps<<7) | (seg<<9); pair = xcd*4+ps (same XCD for both segs)
    int id = blockIdx.x;
    int xcd = id & 7, et = (id >> 3) & 15;
    int rest = id >> 7;
    int ps = rest & 3, seg = rest >> 2;
    int pair = xcd * 4 + ps;
    int b = pair >> 3, h = pair & 7;
    int e0 = et * 64 + w * 16;

    __shared__ unsigned short Kst[2][64][64];
    __shared__ unsigned short Vst[2][64][64];
    __shared__ unsigned short Pt[4][16][76];
    unsigned short* Pw = &Pt[w][0][0];

    const unsigned short* Qrow = Qb + (size_t)(b * NE + e0 + lr) * DMODEL + h * DK;
    bf16x8 q0 = ldb8(Qrow + lh * 8);
    bf16x8 q1 = ldb8(Qrow + 32 + lh * 8);

    const unsigned short* Kg =
        Kb + (size_t)(b * NNODE + seg * 2048) * DMODEL + h * DK;
    const unsigned short* Vg =
        Vt + (size_t)((b * NHEADS + h) * DK) * NNODE + seg * 2048;
    const unsigned long long* mrow = mbits + (size_t)(b * NE + e0) * 64 + seg * 32;

    int srow0 = w * 16 + (l >> 3);
    int scol = l & 7;

    f32x4 oacc[4] = {};
    float lsum[4] = {0.f, 0.f, 0.f, 0.f};

    auto stage = [&](int bf, int cb) {
#pragma unroll
        for (int ii = 0; ii < 2; ++ii) {
            int row = srow0 + ii * 8;
            int cu = scol ^ (row & 7);
            gload16(Kg + (size_t)(cb * 64 + row) * DMODEL + cu * 8,
                    &Kst[bf][w * 16 + ii * 8][0]);
            gload16(Vg + (size_t)row * NNODE + cb * 64 + cu * 8,
                    &Vst[bf][w * 16 + ii * 8][0]);
        }
    };

    unsigned long long mcur[4], mnext[4];

    stage(0, 0);
#pragma unroll
    for (int r = 0; r < 4; ++r) mcur[r] = mrow[(lh * 4 + r) * 64];
    __syncthreads();

    int bf = 0;
    for (int cb = 0; cb < 32; ++cb) {
        if (cb < 31) {
            stage(bf ^ 1, cb + 1);
#pragma unroll
            for (int r = 0; r < 4; ++r) mnext[r] = mrow[(lh * 4 + r) * 64 + cb + 1];
        }
        bf16x8 kf[4][2];
#pragma unroll
        for (int t = 0; t < 4; ++t) {
            int row = t * 16 + lr;
            kf[t][0] = ldb8(&Kst[bf][row][((0 + lh) ^ (lr & 7)) * 8]);
            kf[t][1] = ldb8(&Kst[bf][row][((4 + lh) ^ (lr & 7)) * 8]);
        }
        f32x4 s[4] = {};
#pragma unroll
        for (int t = 0; t < 4; ++t) {
            s[t] = __builtin_amdgcn_mfma_f32_16x16x32_bf16(q0, kf[t][0], s[t], 0, 0, 0);
            s[t] = __builtin_amdgcn_mfma_f32_16x16x32_bf16(q1, kf[t][1], s[t], 0, 0, 0);
        }
        bf16x8 vf[2][4];
#pragma unroll
        for (int kk = 0; kk < 2; ++kk)
#pragma unroll
            for (int dt = 0; dt < 4; ++dt) {
                int row = dt * 16 + lr;
                vf[kk][dt] = ldb8(&Vst[bf][row][((kk * 4 + lh) ^ (lr & 7)) * 8]);
            }
#pragma unroll
        for (int t = 0; t < 4; ++t) {
#pragma unroll
            for (int r = 0; r < 4; ++r) {
                float p = exp2v(s[t][r]);
                unsigned half = (t < 2) ? (unsigned)mcur[r] : (unsigned)(mcur[r] >> 32);
                unsigned bits = half >> ((t & 1) * 16 + lr);
                p = (bits & 1u) ? p : 0.0f;
                s[t][r] = p;
                lsum[r] += p;
            }
            unsigned p01 = cvtpk(s[t][0], s[t][1]);
            unsigned p23 = cvtpk(s[t][2], s[t][3]);
            Pw[(lh * 4 + 0) * 76 + t * 16 + lr] = (unsigned short)p01;
            Pw[(lh * 4 + 1) * 76 + t * 16 + lr] = (unsigned short)(p01 >> 16);
            Pw[(lh * 4 + 2) * 76 + t * 16 + lr] = (unsigned short)p23;
            Pw[(lh * 4 + 3) * 76 + t * 16 + lr] = (unsigned short)(p23 >> 16);
        }
#pragma unroll
        for (int kk = 0; kk < 2; ++kk) {
            bf16x8 pa = ldb8(Pw + lr * 76 + kk * 32 + lh * 8);
#pragma unroll
            for (int dt = 0; dt < 4; ++dt) {
                oacc[dt] = __builtin_amdgcn_mfma_f32_16x16x32_bf16(pa, vf[kk][dt],
                                                                   oacc[dt], 0, 0, 0);
            }
        }
        __syncthreads();
        bf ^= 1;
#pragma unroll
        for (int r = 0; r < 4; ++r) mcur[r] = mnext[r];
    }

    // ---- epilogue: reduce lsum over 16 node-lanes; write f32 partials ----
#pragma unroll
    for (int r = 0; r < 4; ++r) {
        float v = lsum[r];
        v += __shfl_xor(v, 1);
        v += __shfl_xor(v, 2);
        v += __shfl_xor(v, 4);
        v += __shfl_xor(v, 8);
        lsum[r] = v;
    }
    float* Opf = Op + (size_t)seg * (BSZ * NE * DMODEL);
    float* Lpf = Lp + (size_t)seg * (BSZ * NHEADS * NE);
#pragma unroll
    for (int r = 0; r < 4; ++r) {
        size_t row = (size_t)(b * NE + e0 + lh * 4 + r) * DMODEL + h * DK;
#pragma unroll
        for (int dt = 0; dt < 4; ++dt) Opf[row + dt * 16 + lr] = oacc[dt][r];
    }
    if (lr == 0) {
#pragma unroll
        for (int r = 0; r < 4; ++r)
            Lpf[(size_t)(b * NHEADS + h) * NE + e0 + lh * 4 + r] = lsum[r];
    }
}

// ---------------- combine: Ob = (O0+O1)/(L0+L1), bf16 ----------------
__global__ __launch_bounds__(256) void combine2(const float* __restrict__ O0,
                                                const float* __restrict__ O1,
                                                const float* __restrict__ L0,
                                                const float* __restrict__ L1,
                                                unsigned short* __restrict__ Ob) {
    int gi = blockIdx.x * 256 + threadIdx.x;  // 0..262143
    size_t base = (size_t)gi * 8;
    int row = (int)(base >> 9);       // b*NE + e
    int h = ((int)base & 511) >> 6;
    int b = row >> 10, e = row & 1023;
    size_t li = (size_t)(b * NHEADS + h) * NE + e;
    float inv = 1.0f / (L0[li] + L1[li]);
    float4 a0 = *reinterpret_cast<const float4*>(O0 + base);
    float4 a1 = *reinterpret_cast<const float4*>(O0 + base + 4);
    float4 b0 = *reinterpret_cast<const float4*>(O1 + base);
    float4 b1 = *reinterpret_cast<const float4*>(O1 + base + 4);
    unsigned u0 = cvtpk((a0.x + b0.x) * inv, (a0.y + b0.y) * inv);
    unsigned u1 = cvtpk((a0.z + b0.z) * inv, (a0.w + b0.w) * inv);
    unsigned u2 = cvtpk((a1.x + b1.x) * inv, (a1.y + b1.y) * inv);
    unsigned u3 = cvtpk((a1.z + b1.z) * inv, (a1.w + b1.w) * inv);
    u16x8 o;
    o[0] = (unsigned short)u0; o[1] = (unsigned short)(u0 >> 16);
    o[2] = (unsigned short)u1; o[3] = (unsigned short)(u1 >> 16);
    o[4] = (unsigned short)u2; o[5] = (unsigned short)(u2 >> 16);
    o[6] = (unsigned short)u3; o[7] = (unsigned short)(u3 >> 16);
    *reinterpret_cast<u16x8*>(Ob + base) = o;
}

// ---------------- launch ----------------
extern "C" void kernel_launch(void* const* d_in, const int* in_sizes, int n_in,
                              void* d_out, int out_size, void* d_ws, size_t ws_size,
                              hipStream_t stream) {
    const float* queries = (const float*)d_in[0];
    const float* keys = (const float*)d_in[1];
    const int* inc = (const int*)d_in[2];
    const float* Wq = (const float*)d_in[3];
    const float* bq = (const float*)d_in[4];
    const float* Wk = (const float*)d_in[5];
    const float* bk = (const float*)d_in[6];
    const float* Wv = (const float*)d_in[7];
    const float* bv = (const float*)d_in[8];
    const float* Wo = (const float*)d_in[9];
    const float* bo = (const float*)d_in[10];

    char* base = (char*)d_ws;
    // [0,2M) mask bits | [2M,4M) weights bf16 | [4M,8M) qbf | [8M,24M) kbf
    // [24,28M) Qb | [28,44M) Kb | [44,60M) Vt | [60,64M) Ob
    // attn partials OVERLAY dead qbf/kbf: Op0 [4M,12M), Op1 [12M,20M), Lp [20M,20.5M)
    unsigned long long* mbits = (unsigned long long*)base;
    unsigned short* wqb = (unsigned short*)(base + (2u << 20));
    unsigned short* qbf = (unsigned short*)(base + (4u << 20));
    unsigned short* kbf = (unsigned short*)(base + (8u << 20));
    unsigned short* Qb = (unsigned short*)(base + (24u << 20));
    unsigned short* Kb = (unsigned short*)(base + (28u << 20));
    unsigned short* Vt = (unsigned short*)(base + (44u << 20));
    unsigned short* Ob = (unsigned short*)(base + (60u << 20));
    float* Op0 = (float*)(base + (4u << 20));
    float* Lp0 = (float*)(base + (20u << 20));

    conv_all<<<5632, 256, 0, stream>>>((const float4*)queries, (const float4*)keys,
                                       (const float4*)Wq, (const float4*)Wk,
                                       (const float4*)Wv, (const float4*)Wo,
                                       (u16x8*)qbf, (u16x8*)kbf, (u16x8*)wqb);
    maskpack<<<8192, 256, 0, stream>>>(inc, mbits);

    unsigned short* wkb = wqb + DMODEL * DMODEL;
    unsigned short* wvb = wkb + DMODEL * DMODEL;
    unsigned short* wob = wvb + DMODEL * DMODEL;

    // Q projection pre-scaled by log2(e)/sqrt(d_k) = log2(e)/8 (exp2-domain softmax)
    gemm128<0><<<dim3(BSZ * NE / 128, 4), 256, 0, stream>>>(qbf, wqb, bq, Qb,
                                                            0.18033688f);
    gemm128<0><<<dim3(BSZ * NNODE / 128, 4), 256, 0, stream>>>(kbf, wkb, bk, Kb, 1.0f);
    gemm128<1><<<dim3(BSZ * NNODE / 128, 4), 256, 0, stream>>>(kbf, wvb, bv, Vt, 1.0f);

    attn_kernel<<<dim3(1024), 256, 0, stream>>>(Qb, Kb, Vt, mbits, Op0, Lp0);

    combine2<<<dim3(1024), 256, 0, stream>>>(Op0, Op0 + (size_t)BSZ * NE * DMODEL, Lp0,
                                             Lp0 + (size_t)BSZ * NHEADS * NE, Ob);

    gemm128<2><<<dim3(BSZ * NE / 128, 4), 256, 0, stream>>>(Ob, wob, bo, d_out, 1.0f);
}